// Round 7
// baseline (58.944 us; speedup 1.0000x reference)
//
#include <hip/hip_runtime.h>

#define PAD 10
#define CS 128
#define CSP 148           // CS + 2*PAD
#define AH 4000
#define AW 4000
#define RPT 4             // output rows per thread
#define BROWS 8           // rows per block
#define LR 14             // staged rows in LDS
#define LC 140            // staged cols (floats), multiple of 4
#define LF4 ((LR*LC)/4)   // 490 float4 loads to stage

typedef float v2f __attribute__((ext_vector_type(2)));

__device__ __forceinline__ v2f pk_fma(v2f a, v2f b, v2f c) {
    return __builtin_elementwise_fma(a, b, c);
}

// ---- general-path PREP (R5, verified) ----
#define PREPG(S, IXF, IYF)                                                    \
    do {                                                                      \
        const float fx0_ = floorf(IXF), fy0_ = floorf(IYF);                   \
        txs[S] = (IXF) - fx0_; tys[S] = (IYF) - fy0_;                         \
        const int ixi_ = (int)fx0_, iyi_ = (int)fy0_;                         \
        ixis[S] = ixi_; iyis[S] = iyi_;                                       \
        fasts[S] = (ixi_ - 1 >= lo_c) & (ixi_ + 2 <= hi_c) &                  \
                   (iyi_ - 1 >= lo_r) & (iyi_ + 2 <= hi_r);                   \
        int mr_ = gr0 + iyi_ - 1; mr_ = mr_ < 0 ? 0 : (mr_ > AH-4 ? AH-4 : mr_); \
        int mc_ = gc0 + ixi_ - 1; mc_ = mc_ < 0 ? 0 : (mc_ > AW-4 ? AW-4 : mc_); \
        const float* p_ = matrix + (size_t)mr_ * AW + mc_;                    \
        __builtin_memcpy(&qg[S][0], p_,        16);                           \
        __builtin_memcpy(&qg[S][1], p_ + AW,   16);                           \
        __builtin_memcpy(&qg[S][2], p_ + 2*AW, 16);                           \
        __builtin_memcpy(&qg[S][3], p_ + 3*AW, 16);                           \
    } while (0)

__global__ __launch_bounds__(256) void shift_bicubic_kernel(
    const float* __restrict__ matrix,
    const float* __restrict__ theta,
    float* __restrict__ out)
{
    __shared__ float lds[LR*LC];

    const int n   = blockIdx.x;          // tile index 0..1023
    const int i0  = n >> 5;
    const int i1  = n & 31;
    const int c   = threadIdx.x & 127;
    const int sub = threadIdx.x >> 7;
    const int rb  = blockIdx.y * BROWS;
    const int r0  = rb + sub*RPT;
    const int w   = i1 * CS + c;
    const int h0  = i0 * CS + r0;

    const float t00 = theta[n*6+0], t01 = theta[n*6+1], t02 = theta[n*6+2];
    const float t10 = theta[n*6+3], t11 = theta[n*6+4], t12 = theta[n*6+5];

    const float xs  = (2.0f*(float)(c + PAD) + 1.0f) * (1.0f/148.0f) - 1.0f;
    const float ys0 = (2.0f*(float)(r0 + PAD) + 1.0f) * (1.0f/148.0f) - 1.0f;
    const float bx  = fmaf(t00, xs, t02);
    const float by  = fmaf(t10, xs, t12);
    // sample coords advance by exactly t01/t11 per output row
    const float ixf0 = fmaf(fmaf(t01, ys0, bx), 74.0f, 73.5f);
    const float iyf0 = fmaf(fmaf(t11, ys0, by), 74.0f, 73.5f);

    const int gr0 = i0*CS - 2*PAD;
    const int gc0 = i1*CS - 2*PAD;
    const int lo_c = (gc0 < 0) ? -gc0 : 0;
    const int hi_c = (gc0 + CSP - 1 > AW - 1) ? (AW - 1 - gc0) : (CSP - 1);
    const int lo_r = (gr0 < 0) ? -gr0 : 0;
    const int hi_r = (gr0 + CSP - 1 > AH - 1) ? (AH - 1 - gr0) : (CSP - 1);

    // ---- block-uniform footprint from affine corner extremes ----
    const float xsA = (2.0f*(float)(PAD)        + 1.0f)*(1.0f/148.0f) - 1.0f;
    const float xsB = (2.0f*(float)(127 + PAD)  + 1.0f)*(1.0f/148.0f) - 1.0f;
    const float ysA = (2.0f*(float)(rb     + PAD) + 1.0f)*(1.0f/148.0f) - 1.0f;
    const float ysB = (2.0f*(float)(rb + 4 + PAD) + 1.0f)*(1.0f/148.0f) - 1.0f;
    const float ixAA = fmaf(fmaf(t01, ysA, fmaf(t00, xsA, t02)), 74.0f, 73.5f);
    const float ixAB = fmaf(fmaf(t01, ysB, fmaf(t00, xsA, t02)), 74.0f, 73.5f);
    const float ixBA = fmaf(fmaf(t01, ysA, fmaf(t00, xsB, t02)), 74.0f, 73.5f);
    const float ixBB = fmaf(fmaf(t01, ysB, fmaf(t00, xsB, t02)), 74.0f, 73.5f);
    const float iyAA = fmaf(fmaf(t11, ysA, fmaf(t10, xsA, t12)), 74.0f, 73.5f);
    const float iyAB = fmaf(fmaf(t11, ysB, fmaf(t10, xsA, t12)), 74.0f, 73.5f);
    const float iyBA = fmaf(fmaf(t11, ysA, fmaf(t10, xsB, t12)), 74.0f, 73.5f);
    const float iyBB = fmaf(fmaf(t11, ysB, fmaf(t10, xsB, t12)), 74.0f, 73.5f);
    // k in [0,3] adds k*t01 / k*t11
    const float ixmn = fminf(fminf(ixAA, ixAB), fminf(ixBA, ixBB)) + fminf(0.0f, 3.0f*t01);
    const float ixmx = fmaxf(fmaxf(ixAA, ixAB), fmaxf(ixBA, ixBB)) + fmaxf(0.0f, 3.0f*t01);
    const float iymn = fminf(fminf(iyAA, iyAB), fminf(iyBA, iyBB)) + fminf(0.0f, 3.0f*t11);
    const float iymx = fmaxf(fmaxf(iyAA, iyAB), fmaxf(iyBA, iyBB)) + fmaxf(0.0f, 3.0f*t11);

    const int collo = (int)floorf(ixmn) - 1;   // min tap col (tile-local)
    const int colhi = (int)floorf(ixmx) + 2;   // max tap col
    const int rowlo = (int)floorf(iymn) - 1;
    const int rowhi = (int)floorf(iymx) + 2;

    const int cb      = collo - 1;             // staged origin, tile-local (±1 margin)
    const int rbs     = rowlo - 1;
    const int colbase = gc0 + cb;              // staged origin, matrix coords
    const int rowbase = gr0 + rbs;

    const bool lean =
        (colhi - collo <= LC - 3) && (rowhi - rowlo <= LR - 3) &&
        (colbase >= 0) && (colbase <= AW - LC) &&
        (rowbase >= 0) && (rowbase <= AH - LR) &&
        (collo - 1 >= lo_c) && (colhi + 1 <= hi_c) &&
        (rowlo - 1 >= lo_r) && (rowhi + 1 <= hi_r);

    if (lean) {
        // ---- stage 14x140 window (coalesced, 2 float4 per thread) ----
        const float* src0 = matrix + rowbase*AW + colbase;
        {
            const int f   = threadIdx.x;          // < 256 -> row <= 7
            const int row = f / 35, c4 = f % 35;
            float4 v; __builtin_memcpy(&v, src0 + row*AW + c4*4, 16);
            *(float4*)&lds[row*LC + c4*4] = v;
        }
        {
            const int f = threadIdx.x + 256;
            if (f < LF4) {
                const int row = f / 35, c4 = f % 35;
                float4 v; __builtin_memcpy(&v, src0 + row*AW + c4*4, 16);
                *(float4*)&lds[row*LC + c4*4] = v;
            }
        }
        __syncthreads();

        const int lbase0 = -rbs*LC - cb;   // lidx = (iyi-1)*LC + (ixi-1) + lbase0
        int oidx = h0*AW + w;
        #pragma unroll
        for (int k = 0; k < RPT; ++k) {
            const float ixf = fmaf((float)k, t01, ixf0);
            const float iyf = fmaf((float)k, t11, iyf0);
            const float fx = floorf(ixf), fy = floorf(iyf);
            const v2f t = {ixf - fx, iyf - fy};
            const int ixi = (int)fx, iyi = (int)fy;
            const float* lp = &lds[(iyi - 1)*LC + (ixi - 1) + lbase0];

            const v2f s  = 1.0f - t;
            const v2f t2 = t*t, s2 = s*s;
            const v2f w0v = (-0.75f*t)*s2;
            const v2f w3v = (-0.75f*s)*t2;
            const v2f w1v = pk_fma(t2, pk_fma((v2f)1.25f, t, (v2f)(-2.25f)), (v2f)1.0f);
            const v2f w2v = pk_fma(s2, pk_fma((v2f)1.25f, s, (v2f)(-2.25f)), (v2f)1.0f);
            const float wx0=w0v.x, wy0=w0v.y, wx1=w1v.x, wy1=w1v.y;
            const float wx2=w2v.x, wy2=w2v.y, wx3=w3v.x, wy3=w3v.y;

            const float a0 = fmaf(wx3, lp[3],        fmaf(wx2, lp[2],        fmaf(wx1, lp[1],        wx0*lp[0])));
            const float a1 = fmaf(wx3, lp[LC+3],     fmaf(wx2, lp[LC+2],     fmaf(wx1, lp[LC+1],     wx0*lp[LC])));
            const float a2 = fmaf(wx3, lp[2*LC+3],   fmaf(wx2, lp[2*LC+2],   fmaf(wx1, lp[2*LC+1],   wx0*lp[2*LC])));
            const float a3 = fmaf(wx3, lp[3*LC+3],   fmaf(wx2, lp[3*LC+2],   fmaf(wx1, lp[3*LC+1],   wx0*lp[3*LC])));
            const float acc = fmaf(wy3,a3, fmaf(wy2,a2, fmaf(wy1,a1, wy0*a0)));
            __builtin_nontemporal_store(acc, &out[oidx]);
            oidx += AW;
        }
    } else if (w < AW && h0 < AH) {
        // ---- general path (R5, verified) ----
        float  txs[2], tys[2];
        int    ixis[2], iyis[2];
        bool   fasts[2];
        float4 qg[2][4];
        PREPG(0, ixf0, iyf0);
        int oidx = h0*AW + w;
        #pragma unroll
        for (int k = 0; k < RPT; ++k) {
            if (k + 1 < RPT) {
                const float ixfn = fmaf((float)(k+1), t01, ixf0);
                const float iyfn = fmaf((float)(k+1), t11, iyf0);
                PREPG((k+1)&1, ixfn, iyfn);
            }
            __builtin_amdgcn_sched_barrier(0);
            const int   S  = k & 1;
            const float tx = txs[S], ty = tys[S];
            const float A_ = -0.75f, AP2 = 1.25f, mAP3 = -2.25f;
            const float sx = 1.0f - tx, sy = 1.0f - ty;
            const float tx2 = tx*tx, sx2 = sx*sx;
            const float ty2 = ty*ty, sy2 = sy*sy;
            const float wx0 = A_*(tx*sx2);
            const float wx3 = A_*(sx*tx2);
            const float wx1 = fmaf(tx2, fmaf(AP2, tx, mAP3), 1.0f);
            const float wx2 = fmaf(sx2, fmaf(AP2, sx, mAP3), 1.0f);
            const float wy0 = A_*(ty*sy2);
            const float wy3 = A_*(sy*ty2);
            const float wy1 = fmaf(ty2, fmaf(AP2, ty, mAP3), 1.0f);
            const float wy2 = fmaf(sy2, fmaf(AP2, sy, mAP3), 1.0f);

            float acc;
            if (fasts[S]) {
                const float4 q0 = qg[S][0], q1 = qg[S][1], q2 = qg[S][2], q3 = qg[S][3];
                const float a0 = fmaf(wx3,q0.w, fmaf(wx2,q0.z, fmaf(wx1,q0.y, wx0*q0.x)));
                const float a1 = fmaf(wx3,q1.w, fmaf(wx2,q1.z, fmaf(wx1,q1.y, wx0*q1.x)));
                const float a2 = fmaf(wx3,q2.w, fmaf(wx2,q2.z, fmaf(wx1,q2.y, wx0*q2.x)));
                const float a3 = fmaf(wx3,q3.w, fmaf(wx2,q3.z, fmaf(wx1,q3.y, wx0*q3.x)));
                acc = fmaf(wy3,a3, fmaf(wy2,a2, fmaf(wy1,a1, wy0*a0)));
            } else {
                const float wxa[4] = {wx0, wx1, wx2, wx3};
                const float wya[4] = {wy0, wy1, wy2, wy3};
                const int ixi = ixis[S], iyi = iyis[S];
                acc = 0.0f;
                #pragma unroll
                for (int ky = 0; ky < 4; ++ky) {
                    const int row = iyi - 1 + ky;
                    const int gr  = gr0 + row;
                    const bool rok = (row >= 0) & (row < CSP) & (gr >= 0) & (gr < AH);
                    float racc = 0.0f;
                    #pragma unroll
                    for (int kx = 0; kx < 4; ++kx) {
                        const int col = ixi - 1 + kx;
                        const int gc  = gc0 + col;
                        const bool cok = rok & (col >= 0) & (col < CSP) & (gc >= 0) & (gc < AW);
                        const float v = cok ? matrix[(size_t)gr*AW + gc] : 0.0f;
                        racc = fmaf(wxa[kx], v, racc);
                    }
                    acc = fmaf(wya[ky], racc, acc);
                }
            }
            if (h0 + k < AH) __builtin_nontemporal_store(acc, &out[oidx]);
            oidx += AW;
        }
    }
}

extern "C" void kernel_launch(void* const* d_in, const int* in_sizes, int n_in,
                              void* d_out, int out_size, void* d_ws, size_t ws_size,
                              hipStream_t stream) {
    const float* matrix = (const float*)d_in[0];
    const float* theta  = (const float*)d_in[1];
    float* out = (float*)d_out;

    dim3 block(256, 1, 1);
    dim3 grid(1024, CS/BROWS, 1);   // 1024 tiles x 16 row-groups
    shift_bicubic_kernel<<<grid, block, 0, stream>>>(matrix, theta, out);
}

// Round 8
// 50.100 us; speedup vs baseline: 1.1765x; 1.1765x over previous
//
#include <hip/hip_runtime.h>

#define PAD 10
#define CS 128
#define CSP 148           // CS + 2*PAD
#define AH 4000
#define AW 4000
#define RPT 4             // output rows per thread
#define BROWS 8           // rows per block (2 row-groups of RPT)
#define NTILES 1024
#define NBANDS 16
#define NBLK (NTILES*NBANDS)   // 16384, divisible by 8 XCDs

__global__ __launch_bounds__(256) void shift_bicubic_kernel(
    const float* __restrict__ matrix,
    const float* __restrict__ theta,
    float* __restrict__ out)
{
    // XCD-contiguous swizzle: consecutive blockIdx round-robin the 8 XCDs,
    // so give XCD k the contiguous id-range [k*2048, (k+1)*2048) of a
    // tile-major/band-minor ordering. Each XCD then owns a 4-tile-row
    // horizontal stripe (L2-compact); consecutive blocks on a CU are
    // adjacent 8-row bands of the SAME tile (L1 window overlap ~43%).
    const int bid  = blockIdx.x;
    const int sid  = (bid & 7) * (NBLK/8) + (bid >> 3);
    const int tile = sid >> 4;          // 0..1023, row-major over 32x32 tiles
    const int band = sid & 15;          // 0..15
    const int i0   = tile >> 5;
    const int i1   = tile & 31;
    const int c    = threadIdx.x & 127;
    const int sub  = threadIdx.x >> 7;
    const int rb   = band * BROWS;
    const int r0   = rb + sub*RPT;
    const int w    = i1*CS + c;
    const int h0   = i0*CS + r0;
    if (w >= AW || h0 >= AH) return;

    const float t00 = theta[tile*6+0], t01 = theta[tile*6+1], t02 = theta[tile*6+2];
    const float t10 = theta[tile*6+3], t11 = theta[tile*6+4], t12 = theta[tile*6+5];

    const float xs  = (2.0f*(float)(c + PAD) + 1.0f) * (1.0f/148.0f) - 1.0f;
    const float ys0 = (2.0f*(float)(r0 + PAD) + 1.0f) * (1.0f/148.0f) - 1.0f;
    const float bx  = fmaf(t00, xs, t02);
    const float by  = fmaf(t10, xs, t12);
    // sample coords advance by exactly t01/t11 per output row
    const float ixf0 = fmaf(fmaf(t01, ys0, bx), 74.0f, 73.5f);
    const float iyf0 = fmaf(fmaf(t11, ys0, by), 74.0f, 73.5f);

    const int gr0 = i0*CS - 2*PAD;
    const int gc0 = i1*CS - 2*PAD;
    const int lo_c = (gc0 < 0) ? -gc0 : 0;
    const int hi_c = (gc0 + CSP - 1 > AW - 1) ? (AW - 1 - gc0) : (CSP - 1);
    const int lo_r = (gr0 < 0) ? -gr0 : 0;
    const int hi_r = (gr0 + CSP - 1 > AH - 1) ? (AH - 1 - gr0) : (CSP - 1);

    // ---------------- phase A: coords + issue ALL 16 loads -----------------
    float tx[RPT], ty[RPT];
    int   ixi[RPT], iyi[RPT];
    bool  fast[RPT];
    float4 q[RPT][4];

    #pragma unroll
    for (int k = 0; k < RPT; ++k) {
        const float ixf = fmaf((float)k, t01, ixf0);
        const float iyf = fmaf((float)k, t11, iyf0);
        const float fx = floorf(ixf), fy = floorf(iyf);
        tx[k] = ixf - fx;  ty[k] = iyf - fy;
        const int xi = (int)fx, yi = (int)fy;
        ixi[k] = xi;  iyi[k] = yi;
        fast[k] = (xi - 1 >= lo_c) & (xi + 2 <= hi_c) &
                  (yi - 1 >= lo_r) & (yi + 2 <= hi_r);
        // clamped (always-safe) footprint base
        int mr = gr0 + yi - 1;  mr = mr < 0 ? 0 : (mr > AH-4 ? AH-4 : mr);
        int mc = gc0 + xi - 1;  mc = mc < 0 ? 0 : (mc > AW-4 ? AW-4 : mc);
        const float* p = matrix + (size_t)mr*AW + mc;
        __builtin_memcpy(&q[k][0], p,        16);
        __builtin_memcpy(&q[k][1], p + AW,   16);
        __builtin_memcpy(&q[k][2], p + 2*AW, 16);
        __builtin_memcpy(&q[k][3], p + 3*AW, 16);
    }
    // fence: the 16 loads above may not sink below; consumers may not hoist.
    __builtin_amdgcn_sched_barrier(0);

    // ---------------- phase B: weights + consume ---------------------------
    int oidx = h0*AW + w;
    #pragma unroll
    for (int k = 0; k < RPT; ++k) {
        const float txk = tx[k], tyk = ty[k];
        const float A_ = -0.75f, AP2 = 1.25f, mAP3 = -2.25f;
        const float sx = 1.0f - txk, sy = 1.0f - tyk;
        const float tx2 = txk*txk, sx2 = sx*sx;
        const float ty2 = tyk*tyk, sy2 = sy*sy;
        const float wx0 = A_*(txk*sx2);
        const float wx3 = A_*(sx*tx2);
        const float wx1 = fmaf(tx2, fmaf(AP2, txk, mAP3), 1.0f);
        const float wx2 = fmaf(sx2, fmaf(AP2, sx, mAP3), 1.0f);
        const float wy0 = A_*(tyk*sy2);
        const float wy3 = A_*(sy*ty2);
        const float wy1 = fmaf(ty2, fmaf(AP2, tyk, mAP3), 1.0f);
        const float wy2 = fmaf(sy2, fmaf(AP2, sy, mAP3), 1.0f);

        float acc;
        if (fast[k]) {
            const float4 q0 = q[k][0], q1 = q[k][1], q2 = q[k][2], q3 = q[k][3];
            const float a0 = fmaf(wx3,q0.w, fmaf(wx2,q0.z, fmaf(wx1,q0.y, wx0*q0.x)));
            const float a1 = fmaf(wx3,q1.w, fmaf(wx2,q1.z, fmaf(wx1,q1.y, wx0*q1.x)));
            const float a2 = fmaf(wx3,q2.w, fmaf(wx2,q2.z, fmaf(wx1,q2.y, wx0*q2.x)));
            const float a3 = fmaf(wx3,q3.w, fmaf(wx2,q3.z, fmaf(wx1,q3.y, wx0*q3.x)));
            acc = fmaf(wy3,a3, fmaf(wy2,a2, fmaf(wy1,a1, wy0*a0)));
        } else {
            const float wxa[4] = {wx0, wx1, wx2, wx3};
            const float wya[4] = {wy0, wy1, wy2, wy3};
            const int xi = ixi[k], yi = iyi[k];
            acc = 0.0f;
            #pragma unroll
            for (int ky = 0; ky < 4; ++ky) {
                const int row = yi - 1 + ky;
                const int gr  = gr0 + row;
                const bool rok = (row >= 0) & (row < CSP) & (gr >= 0) & (gr < AH);
                float racc = 0.0f;
                #pragma unroll
                for (int kx = 0; kx < 4; ++kx) {
                    const int col = xi - 1 + kx;
                    const int gc  = gc0 + col;
                    const bool cok = rok & (col >= 0) & (col < CSP) & (gc >= 0) & (gc < AW);
                    const float v = cok ? matrix[(size_t)gr*AW + gc] : 0.0f;
                    racc = fmaf(wxa[kx], v, racc);
                }
                acc = fmaf(wya[ky], racc, acc);
            }
        }
        if (h0 + k < AH) __builtin_nontemporal_store(acc, &out[oidx]);
        oidx += AW;
    }
}

extern "C" void kernel_launch(void* const* d_in, const int* in_sizes, int n_in,
                              void* d_out, int out_size, void* d_ws, size_t ws_size,
                              hipStream_t stream) {
    const float* matrix = (const float*)d_in[0];
    const float* theta  = (const float*)d_in[1];
    float* out = (float*)d_out;

    dim3 block(256, 1, 1);
    dim3 grid(NBLK, 1, 1);   // flat, swizzled in-kernel
    shift_bicubic_kernel<<<grid, block, 0, stream>>>(matrix, theta, out);
}

// Round 9
// 43.188 us; speedup vs baseline: 1.3648x; 1.1601x over previous
//
#include <hip/hip_runtime.h>

#define PAD 10
#define CS 128
#define CSP 148           // CS + 2*PAD
#define AH 4000
#define AW 4000
#define RPT 8             // output rows per thread
#define BROWS 16          // rows per block (2 row-groups of RPT)
#define NTILES 1024
#define NBANDS 8
#define NBLK (NTILES*NBANDS)   // 8192, divisible by 8 XCDs

// depth-2 pipeline PREP (R5, verified): coords, fast flag, 4 clamped loads
#define PREPG(S, IXF, IYF)                                                    \
    do {                                                                      \
        const float fx0_ = floorf(IXF), fy0_ = floorf(IYF);                   \
        txs[S] = (IXF) - fx0_; tys[S] = (IYF) - fy0_;                         \
        const int ixi_ = (int)fx0_, iyi_ = (int)fy0_;                         \
        ixis[S] = ixi_; iyis[S] = iyi_;                                       \
        fasts[S] = (ixi_ - 1 >= lo_c) & (ixi_ + 2 <= hi_c) &                  \
                   (iyi_ - 1 >= lo_r) & (iyi_ + 2 <= hi_r);                   \
        int mr_ = gr0 + iyi_ - 1; mr_ = mr_ < 0 ? 0 : (mr_ > AH-4 ? AH-4 : mr_); \
        int mc_ = gc0 + ixi_ - 1; mc_ = mc_ < 0 ? 0 : (mc_ > AW-4 ? AW-4 : mc_); \
        const float* p_ = matrix + (size_t)mr_ * AW + mc_;                    \
        __builtin_memcpy(&qg[S][0], p_,        16);                           \
        __builtin_memcpy(&qg[S][1], p_ + AW,   16);                           \
        __builtin_memcpy(&qg[S][2], p_ + 2*AW, 16);                           \
        __builtin_memcpy(&qg[S][3], p_ + 3*AW, 16);                           \
    } while (0)

__global__ __launch_bounds__(256) void shift_bicubic_kernel(
    const float* __restrict__ matrix,
    const float* __restrict__ theta,
    float* __restrict__ out)
{
    // XCD-contiguous swizzle (R8, verified: FETCH 40->31.5 MB):
    // XCD k owns sids [k*1024,(k+1)*1024) = a 4-tile-row horizontal stripe;
    // tile-major/band-minor so consecutive blocks share a tile.
    const int bid  = blockIdx.x;
    const int sid  = (bid & 7) * (NBLK/8) + (bid >> 3);
    const int tile = sid >> 3;          // 0..1023, row-major over 32x32 tiles
    const int band = sid & 7;           // 0..7
    const int i0   = tile >> 5;
    const int i1   = tile & 31;
    const int c    = threadIdx.x & 127;
    const int sub  = threadIdx.x >> 7;
    const int rb   = band * BROWS;
    const int r0   = rb + sub*RPT;
    const int w    = i1*CS + c;
    const int h0   = i0*CS + r0;
    if (w >= AW || h0 >= AH) return;

    const float t00 = theta[tile*6+0], t01 = theta[tile*6+1], t02 = theta[tile*6+2];
    const float t10 = theta[tile*6+3], t11 = theta[tile*6+4], t12 = theta[tile*6+5];

    const float xs  = (2.0f*(float)(c + PAD) + 1.0f) * (1.0f/148.0f) - 1.0f;
    const float ys0 = (2.0f*(float)(r0 + PAD) + 1.0f) * (1.0f/148.0f) - 1.0f;
    const float bx  = fmaf(t00, xs, t02);
    const float by  = fmaf(t10, xs, t12);
    // sample coords advance by exactly t01/t11 per output row
    const float ixf0 = fmaf(fmaf(t01, ys0, bx), 74.0f, 73.5f);
    const float iyf0 = fmaf(fmaf(t11, ys0, by), 74.0f, 73.5f);

    const int gr0 = i0*CS - 2*PAD;
    const int gc0 = i1*CS - 2*PAD;
    const int lo_c = (gc0 < 0) ? -gc0 : 0;
    const int hi_c = (gc0 + CSP - 1 > AW - 1) ? (AW - 1 - gc0) : (CSP - 1);
    const int lo_r = (gr0 < 0) ? -gr0 : 0;
    const int hi_r = (gr0 + CSP - 1 > AH - 1) ? (AH - 1 - gr0) : (CSP - 1);

    // depth-2 pipeline state
    float  txs[2], tys[2];
    int    ixis[2], iyis[2];
    bool   fasts[2];
    float4 qg[2][4];

    PREPG(0, ixf0, iyf0);

    int oidx = h0*AW + w;
    #pragma unroll
    for (int k = 0; k < RPT; ++k) {
        // ---- issue next pixel's loads (slot (k+1)&1) ----
        if (k + 1 < RPT) {
            const float ixfn = fmaf((float)(k+1), t01, ixf0);
            const float iyfn = fmaf((float)(k+1), t11, iyf0);
            PREPG((k+1)&1, ixfn, iyfn);
        }
        // fence: loads above may not sink; consumers below may not hoist
        __builtin_amdgcn_sched_barrier(0);

        // ---- consume slot k&1 ----
        const int   S  = k & 1;
        const float tx = txs[S], ty = tys[S];
        const float A_ = -0.75f, AP2 = 1.25f, mAP3 = -2.25f;
        const float sx = 1.0f - tx, sy = 1.0f - ty;
        const float tx2 = tx*tx, sx2 = sx*sx;
        const float ty2 = ty*ty, sy2 = sy*sy;
        const float wx0 = A_*(tx*sx2);
        const float wx3 = A_*(sx*tx2);
        const float wx1 = fmaf(tx2, fmaf(AP2, tx, mAP3), 1.0f);
        const float wx2 = fmaf(sx2, fmaf(AP2, sx, mAP3), 1.0f);
        const float wy0 = A_*(ty*sy2);
        const float wy3 = A_*(sy*ty2);
        const float wy1 = fmaf(ty2, fmaf(AP2, ty, mAP3), 1.0f);
        const float wy2 = fmaf(sy2, fmaf(AP2, sy, mAP3), 1.0f);

        float acc;
        if (fasts[S]) {
            const float4 q0 = qg[S][0], q1 = qg[S][1], q2 = qg[S][2], q3 = qg[S][3];
            const float a0 = fmaf(wx3,q0.w, fmaf(wx2,q0.z, fmaf(wx1,q0.y, wx0*q0.x)));
            const float a1 = fmaf(wx3,q1.w, fmaf(wx2,q1.z, fmaf(wx1,q1.y, wx0*q1.x)));
            const float a2 = fmaf(wx3,q2.w, fmaf(wx2,q2.z, fmaf(wx1,q2.y, wx0*q2.x)));
            const float a3 = fmaf(wx3,q3.w, fmaf(wx2,q3.z, fmaf(wx1,q3.y, wx0*q3.x)));
            acc = fmaf(wy3,a3, fmaf(wy2,a2, fmaf(wy1,a1, wy0*a0)));
        } else {
            const float wxa[4] = {wx0, wx1, wx2, wx3};
            const float wya[4] = {wy0, wy1, wy2, wy3};
            const int ixi = ixis[S], iyi = iyis[S];
            acc = 0.0f;
            #pragma unroll
            for (int ky = 0; ky < 4; ++ky) {
                const int row = iyi - 1 + ky;
                const int gr  = gr0 + row;
                const bool rok = (row >= 0) & (row < CSP) & (gr >= 0) & (gr < AH);
                float racc = 0.0f;
                #pragma unroll
                for (int kx = 0; kx < 4; ++kx) {
                    const int col = ixi - 1 + kx;
                    const int gc  = gc0 + col;
                    const bool cok = rok & (col >= 0) & (col < CSP) & (gc >= 0) & (gc < AW);
                    const float v = cok ? matrix[(size_t)gr*AW + gc] : 0.0f;
                    racc = fmaf(wxa[kx], v, racc);
                }
                acc = fmaf(wya[ky], racc, acc);
            }
        }
        if (h0 + k < AH) __builtin_nontemporal_store(acc, &out[oidx]);
        oidx += AW;
    }
}

extern "C" void kernel_launch(void* const* d_in, const int* in_sizes, int n_in,
                              void* d_out, int out_size, void* d_ws, size_t ws_size,
                              hipStream_t stream) {
    const float* matrix = (const float*)d_in[0];
    const float* theta  = (const float*)d_in[1];
    float* out = (float*)d_out;

    dim3 block(256, 1, 1);
    dim3 grid(NBLK, 1, 1);   // flat, swizzled in-kernel
    shift_bicubic_kernel<<<grid, block, 0, stream>>>(matrix, theta, out);
}